// Round 4
// baseline (106.296 us; speedup 1.0000x reference)
//
#include <hip/hip_runtime.h>

#define HH 128
#define WW 128
#define HW 16384
#define KK 16
#define NPTS 16384
#define FEAT 64
#define RADIUS2 4.0f
#define EPSV 1e-10f
#define CAP 16          // bucket capacity per cell (Poisson(1): P(>16) ~ 1e-14)

// ---------------- kernel 1: project + direct bucket scatter ----------------
// buckets are slot-major: buckets[s*HW + cell], s in [0,CAP)
__global__ void project_scatter(const float* __restrict__ pts,
                                const float* __restrict__ intr,
                                int* __restrict__ cell_count,
                                float4* __restrict__ buckets) {
    int n = blockIdx.x * blockDim.x + threadIdx.x;
    if (n >= NPTS) return;
    float fx = intr[0], cx = intr[2], fy = intr[4], cy = intr[5];
    float x = pts[3 * n], y = pts[3 * n + 1], z = pts[3 * n + 2];
    bool valid = z > 1e-6f;
    float sz = valid ? z : 1.0f;
    float u = x * fx / sz + cx;
    float v = y * fy / sz + cy;
    if (!valid) return;  // invalid points project to FAR -> never within radius
    int cu = min(max((int)floorf(u), 0), WW - 1);
    int cv = min(max((int)floorf(v), 0), HH - 1);
    int cell = cv * WW + cu;
    int slot = atomicAdd(&cell_count[cell], 1);
    if (slot < CAP)
        buckets[slot * HW + cell] = make_float4(u, v, z, __int_as_float(n));
}

// ---------------- kernel 2: tiled KNN render + fused feats ----------------
// block = 64 threads; tile = 8 wide x 4 tall = 32 pixels, 2 lanes/pixel; grid 512
__global__ __launch_bounds__(64) void render_kernel(
        const float4* __restrict__ buckets,
        const int* __restrict__ cell_count,
        const float* __restrict__ colors,
        const float* __restrict__ feats,
        float* __restrict__ out_depth, float* __restrict__ out_colors,
        float* __restrict__ out_feats, float* __restrict__ out_mask) {
    __shared__ float4 pts_s[CAP * 96];   // [slot][window-cell], 24 KB
    __shared__ int    cnt_s[96];
    __shared__ float  knw_s[32][KK];
    __shared__ int    kni_s[32][KK];

    int tid = threadIdx.x;
    int tile = blockIdx.x;
    int j0 = (tile & 15) * 8;
    int i0 = (tile >> 4) * 4;

    // ---- stage window cell counts (8 rows x 12 cols), track max ----
    int mymax = 0;
    for (int idx = tid; idx < 96; idx += 64) {
        int r = idx / 12, c = idx - r * 12;
        int ci = i0 - 2 + r, cj = j0 - 2 + c;
        int cnt = 0;
        if (ci >= 0 && ci < HH && cj >= 0 && cj < WW)
            cnt = min(cell_count[ci * WW + cj], CAP);
        cnt_s[idx] = cnt;
        mymax = max(mymax, cnt);
    }
#pragma unroll
    for (int d = 32; d; d >>= 1) mymax = max(mymax, __shfl_xor(mymax, d));
    int M = mymax;  // uniform across the single wave
    __syncthreads();

    // ---- stage bucket slots 0..M-1 for all 96 window cells ----
    for (int s = 0; s < M; ++s) {
        for (int idx = tid; idx < 96; idx += 64) {
            int r = idx / 12, c = idx - r * 12;
            int ci = i0 - 2 + r, cj = j0 - 2 + c;
            if (s < cnt_s[idx])
                pts_s[s * 96 + idx] = buckets[s * HW + ci * WW + cj];
        }
    }
    __syncthreads();

    // ---- per-pixel KNN scan, 2 lanes/pixel ----
    int lp = tid >> 1, lane = tid & 1;
    int li = lp >> 3, lj = lp & 7;
    int i = i0 + li, j = j0 + lj;
    int p = i * WW + j;
    float px = j + 0.5f, py = i + 0.5f;

    float bd[KK];
    int   bt[KK];
#pragma unroll
    for (int k = 0; k < KK; ++k) { bd[k] = 1e30f; bt[k] = -1; }

#pragma unroll
    for (int dr = 0; dr < 5; ++dr) {
        int r = li + dr;          // 0..7
#pragma unroll
        for (int dc = 0; dc < 5; ++dc) {
            int c = lj + dc;      // 0..11
            int wc = r * 12 + c;
            int cnt = cnt_s[wc];
            for (int s = lane; s < cnt; s += 2) {
                float4 pt = pts_s[s * 96 + wc];
                float du = pt.x - px, dv = pt.y - py;
                float d2 = du * du + dv * dv;
                bool ok = d2 < RADIUS2;
                float dd = ok ? d2 : 1e30f;
                int tt = ok ? (s * 96 + wc) : -1;
#pragma unroll
                for (int k = 0; k < KK; ++k) {
                    bool cc = dd < bd[k];
                    float nb = cc ? dd : bd[k];
                    dd = cc ? bd[k] : dd;
                    int nt = cc ? tt : bt[k];
                    tt = cc ? bt[k] : tt;
                    bd[k] = nb; bt[k] = nt;
                }
            }
        }
    }

    // ---- cross-lane bitonic min-merge: each lane keeps 8 disjoint winners ----
    float mb[8]; int mt[8];
#pragma unroll
    for (int k = 0; k < 8; ++k) {
        float obd = __shfl_xor(bd[15 - k], 1);
        int   obt = __shfl_xor(bt[15 - k], 1);
        bool take = obd < bd[k];
        mb[k] = take ? obd : bd[k];
        mt[k] = take ? obt : bt[k];
    }

    // ---- per-lane epilogue over 8 winners ----
    float wv[8], dv8[8];
    int idv[8];
    float wsum_l = 0.f;
    int any_l = 0;
#pragma unroll
    for (int k = 0; k < 8; ++k) {
        bool valid = mt[k] >= 0;
        float4 pt = pts_s[valid ? mt[k] : 0];
        float wk = valid ? __expf(-mb[k]) : 0.f;
        wv[k] = wk; wsum_l += wk;
        dv8[k] = valid ? pt.z : 0.f;
        idv[k] = valid ? __float_as_int(pt.w) : -1;
        any_l |= valid ? 1 : 0;
    }
    float wsum = wsum_l + __shfl_xor(wsum_l, 1);
    float inv = 1.0f / (wsum + EPSV);

    float cr[8], cg[8], cbl[8];
#pragma unroll
    for (int k = 0; k < 8; ++k) {
        int n3 = idv[k] >= 0 ? 3 * idv[k] : 0;
        cr[k] = colors[n3];
        cg[k] = colors[n3 + 1];
        cbl[k] = colors[n3 + 2];
    }

    float dsum = 0.f, c0 = 0.f, c1 = 0.f, c2 = 0.f;
#pragma unroll
    for (int k = 0; k < 8; ++k) {
        float wk = wv[k] * inv;
        kni_s[lp][lane * 8 + k] = idv[k];
        knw_s[lp][lane * 8 + k] = wk;
        dsum += dv8[k] * wk;
        c0 += cr[k] * wk;
        c1 += cg[k] * wk;
        c2 += cbl[k] * wk;
    }

    dsum += __shfl_xor(dsum, 1);
    c0 += __shfl_xor(c0, 1);
    c1 += __shfl_xor(c1, 1);
    c2 += __shfl_xor(c2, 1);
    any_l |= __shfl_xor(any_l, 1);

    if (lane == 0) {
        out_depth[p] = dsum;
        out_colors[3 * p]     = c0;
        out_colors[3 * p + 1] = c1;
        out_colors[3 * p + 2] = c2;
        out_mask[p] = any_l ? 1.0f : 0.0f;
    }
    __syncthreads();

    // ---- fused feats: lane f = tid, two pixels in flight ----
    int f = tid;
    for (int q = 0; q < 32; q += 2) {
        float acc0 = 0.f, acc1 = 0.f;
#pragma unroll
        for (int k = 0; k < KK; ++k) {
            int n0 = kni_s[q][k];
            int n1 = kni_s[q + 1][k];
            float w0 = knw_s[q][k];
            float w1 = knw_s[q + 1][k];
            float f0 = feats[(n0 >= 0 ? n0 : 0) * FEAT + f];
            float f1 = feats[(n1 >= 0 ? n1 : 0) * FEAT + f];
            acc0 = fmaf(w0, f0, acc0);
            acc1 = fmaf(w1, f1, acc1);
        }
        int p0 = (i0 + (q >> 3)) * WW + j0 + (q & 7);
        int p1 = (i0 + ((q + 1) >> 3)) * WW + j0 + ((q + 1) & 7);
        out_feats[p0 * FEAT + f] = acc0;
        out_feats[p1 * FEAT + f] = acc1;
    }
}

extern "C" void kernel_launch(void* const* d_in, const int* in_sizes, int n_in,
                              void* d_out, int out_size, void* d_ws, size_t ws_size,
                              hipStream_t stream) {
    const float* pts    = (const float*)d_in[0];
    const float* colors = (const float*)d_in[1];
    const float* feats  = (const float*)d_in[2];
    const float* intr   = (const float*)d_in[3];

    float* out = (float*)d_out;
    float* out_depth  = out;                  // HW
    float* out_colors = out + HW;             // HW*3
    float* out_feats  = out + HW * 4;         // HW*64
    float* out_mask   = out + HW * 68;        // HW

    char* ws = (char*)d_ws;
    int* cell_count  = (int*)ws;                         // 64 KB
    float4* buckets  = (float4*)(ws + HW * sizeof(int)); // CAP*HW*16B = 4 MB

    hipMemsetAsync(cell_count, 0, HW * sizeof(int), stream);
    project_scatter<<<NPTS / 256, 256, 0, stream>>>(pts, intr, cell_count, buckets);
    render_kernel<<<512, 64, 0, stream>>>(buckets, cell_count, colors, feats,
                                          out_depth, out_colors, out_feats, out_mask);
}